// Round 16
// baseline (1058.734 us; speedup 1.0000x reference)
//
#include <hip/hip_runtime.h>
#include <hip/hip_bf16.h>

typedef __attribute__((ext_vector_type(8))) __bf16 bf16x8v;
typedef __attribute__((ext_vector_type(4))) float f32x4;
typedef __attribute__((ext_vector_type(4))) unsigned short u16x4;
typedef __attribute__((ext_vector_type(8))) unsigned short u16x8;

#define LN_EPS 1e-6f

__device__ __forceinline__ unsigned short f2bf(float f) {
  union { float f; unsigned int u; } v; v.f = f;
  unsigned int r = v.u + 0x7fffu + ((v.u >> 16) & 1u);  // RNE
  return (unsigned short)(r >> 16);
}
__device__ __forceinline__ float bf2f(unsigned short u) {
  union { unsigned int u; float f; } v; v.u = ((unsigned int)u) << 16;
  return v.f;
}
__device__ __forceinline__ float elu1(float x) {
  return x > 0.f ? x + 1.f : __expf(x);  // elu(x)+1
}
__device__ __forceinline__ void gload16(const void* g, void* l) {
  __builtin_amdgcn_global_load_lds((__attribute__((address_space(1))) void*)g,
                                   (__attribute__((address_space(3))) void*)l,
                                   16, 0, 0);
}

// ---------------- f32 -> bf16 convert (vectorized) ----------------
__global__ __launch_bounds__(256) void cvt_f32_bf16(const float* __restrict__ in,
                                                    unsigned short* __restrict__ out, long n) {
  long stride = (long)gridDim.x * 256 * 8;
  for (long i = ((long)blockIdx.x * 256 + threadIdx.x) * 8; i < n; i += stride) {
    float4 a = *(const float4*)(in + i);
    float4 b = *(const float4*)(in + i + 4);
    u16x8 o;
    o[0] = f2bf(a.x); o[1] = f2bf(a.y); o[2] = f2bf(a.z); o[3] = f2bf(a.w);
    o[4] = f2bf(b.x); o[5] = f2bf(b.y); o[6] = f2bf(b.z); o[7] = f2bf(b.w);
    *(u16x8*)(out + i) = o;
  }
}

// ---------- transpose + convert, 4 matrices in one launch (z selects) ----------
struct Tr4Args { const float* src[4]; unsigned short* dst[4]; };
__global__ __launch_bounds__(256) void tr_cvt4(Tr4Args t4) {
  __shared__ float t[64][65];
  const float* in = t4.src[blockIdx.z];
  unsigned short* out = t4.dst[blockIdx.z];
  int r0 = blockIdx.y * 64, c0 = blockIdx.x * 64;
  for (int idx = threadIdx.x; idx < 4096; idx += 256) {
    int r = idx >> 6, c = idx & 63;
    t[r][c] = in[(long)(r0 + r) * 2048 + c0 + c];
  }
  __syncthreads();
  for (int idx = threadIdx.x; idx < 4096; idx += 256) {
    int c = idx >> 6, r = idx & 63;
    out[(long)(c0 + c) * 2048 + r0 + r] = f2bf(t[r][c]);
  }
}

// ---------------- column sum over `rows` rows per batch (bf16 in, f32 out) ----------------
__global__ __launch_bounds__(256) void colsum_bf16(const unsigned short* __restrict__ in,
                                                   float* __restrict__ out, int rows, float scale) {
  int b = blockIdx.y;
  int col = blockIdx.x * 256 + threadIdx.x;
  const unsigned short* p = in + (long)b * rows * 2048 + col;
  float acc = 0.f;
  for (int s = 0; s < rows; ++s) acc += bf2f(p[(long)s * 2048]);
  out[(long)b * 2048 + col] = acc * scale;
}

// ---------------- srow: two-stage k-split rank-64 matmul (R12-validated) ----------------
__global__ __launch_bounds__(256) void srow_part(const float* __restrict__ summ,
                                                 const float* __restrict__ Wo2,
                                                 float* __restrict__ part) {
  int col = blockIdx.x * 256 + threadIdx.x;
  int b = blockIdx.y;
  int k0 = blockIdx.z * 256;
  const float* s = summ + (long)b * 2048 + k0;
  const float* w = Wo2 + (long)k0 * 2048 + col;
  float acc = 0.f;
#pragma unroll 8
  for (int k = 0; k < 256; ++k) acc += s[k] * w[(long)k * 2048];
  part[((long)blockIdx.z * 64 + b) * 2048 + col] = acc;
}
__global__ __launch_bounds__(256) void srow_sum(const float* __restrict__ part,
                                                float* __restrict__ srow) {
  int col = blockIdx.x * 256 + threadIdx.x;
  int b = blockIdx.y;
  float acc = 0.f;
#pragma unroll
  for (int kb = 0; kb < 8; ++kb) acc += part[((long)kb * 64 + b) * 2048 + col];
  srow[(long)b * 2048 + col] = acc;
}

// ---------------- LayerNorm over rows of 2048 (bf16 z input) ----------------
__global__ __launch_bounds__(256) void ln_k(const unsigned short* __restrict__ z,
                                            const float* __restrict__ gamma,
                                            const float* __restrict__ beta,
                                            float* __restrict__ out) {
  long row = blockIdx.x;
  int t = threadIdx.x;
  u16x8 zv = *(const u16x8*)(z + row * 2048 + t * 8);
  float zf[8];
  float s = 0.f, q = 0.f;
#pragma unroll
  for (int j = 0; j < 8; ++j) {
    zf[j] = bf2f(zv[j]);
    s += zf[j];
    q += zf[j] * zf[j];
  }
#pragma unroll
  for (int o = 32; o >= 1; o >>= 1) { s += __shfl_xor(s, o); q += __shfl_xor(q, o); }
  __shared__ float ss[4], qq[4];
  if ((t & 63) == 0) { ss[t >> 6] = s; qq[t >> 6] = q; }
  __syncthreads();
  s = ss[0] + ss[1] + ss[2] + ss[3];
  q = qq[0] + qq[1] + qq[2] + qq[3];
  float mu = s * (1.f / 2048.f);
  float var = q * (1.f / 2048.f) - mu * mu;
  float rstd = rsqrtf(var + LN_EPS);
  float4 g1 = *(const float4*)(gamma + t * 8);
  float4 g2 = *(const float4*)(gamma + t * 8 + 4);
  float4 b1 = *(const float4*)(beta + t * 8);
  float4 b2 = *(const float4*)(beta + t * 8 + 4);
  float4 o1, o2;
  o1.x = (zf[0] - mu) * rstd * g1.x + b1.x;
  o1.y = (zf[1] - mu) * rstd * g1.y + b1.y;
  o1.z = (zf[2] - mu) * rstd * g1.z + b1.z;
  o1.w = (zf[3] - mu) * rstd * g1.w + b1.w;
  o2.x = (zf[4] - mu) * rstd * g2.x + b2.x;
  o2.y = (zf[5] - mu) * rstd * g2.y + b2.y;
  o2.z = (zf[6] - mu) * rstd * g2.z + b2.z;
  o2.w = (zf[7] - mu) * rstd * g2.w + b2.w;
  *(float4*)(out + row * 2048 + t * 8) = o1;
  *(float4*)(out + row * 2048 + t * 8 + 4) = o2;
}

struct GemmArgs {
  const unsigned short* A; long lda, sAb, sAh;   // element strides
  const unsigned short* B; long ldb, sBb, sBh;
  char* C; long ldc, sCb, sCh;                   // ldc elements, sC* bytes
  int K;
  const float* aux; long sXb, sXh;               // bias or divisor (element strides)
  const unsigned short* residb;                  // EPI 5 (bf16 residual)
  const float* srow;                             // EPI 5
  unsigned short* out2;                          // EPI 6 (qact)
  const float* bk2;                              // EPI 6
  const float* bv2;                              // EPI 6
  unsigned short* kact2;                         // EPI 6
  unsigned short* vt2;                           // EPI 6
};

// ---------------- shared epilogue (per 16x16 fragment) ----------------
// EPI 3: scores divide->bf16 | EPI 4: plain bf16 | EPI 5: z=v+bias+resid+srow -> bf16
// EPI 6: fused QKV — wsel=gcol>>11: 0=qproj(bf16 raw + elu), 1=k elu, 2=v transposed
template <int EPI>
__device__ __forceinline__ void epi_frag(const GemmArgs& g, char* Cb, int bz, int hz,
                                         long grow0, long gcol, f32x4 v) {
  if (EPI == 6) {
    const int wsel = (int)(gcol >> 11);
    const long cw = gcol & 2047;
    if (wsel == 0) {
      const float bias = g.aux[cw];
      unsigned short* Ch = (unsigned short*)Cb;
#pragma unroll
      for (int rr = 0; rr < 4; ++rr) {
        const long idx = (grow0 + rr) * 2048 + cw;
        const float vv = v[rr] + bias;
        Ch[idx] = f2bf(vv);
        g.out2[idx] = f2bf(elu1(vv));
      }
    } else if (wsel == 1) {
      const float bias = g.bk2[cw];
#pragma unroll
      for (int rr = 0; rr < 4; ++rr)
        g.kact2[(grow0 + rr) * 2048 + cw] = f2bf(elu1(v[rr] + bias));
    } else {
      const float bias = g.bv2[cw];
      const long batch = grow0 >> 8;
      const int sloc = (int)(grow0 & 255);
      u16x4 pk;
#pragma unroll
      for (int rr = 0; rr < 4; ++rr) pk[rr] = f2bf(v[rr] + bias);
      *(u16x4*)(g.vt2 + (batch * 2048 + cw) * 256 + sloc) = pk;
    }
  } else if (EPI == 3) {
    const float* divs = g.aux + bz * g.sXb + hz * g.sXh;
    const float d = divs[gcol] + LN_EPS;
    unsigned short* Ch = (unsigned short*)Cb;
#pragma unroll
    for (int rr = 0; rr < 4; ++rr)
      Ch[(grow0 + rr) * g.ldc + gcol] = f2bf(v[rr] / d);
  } else if (EPI == 4) {
    unsigned short* Ch = (unsigned short*)Cb;
#pragma unroll
    for (int rr = 0; rr < 4; ++rr)
      Ch[(grow0 + rr) * g.ldc + gcol] = f2bf(v[rr]);
  } else {  // EPI 5
    const float bias = g.aux[gcol];
    unsigned short* Ch = (unsigned short*)Cb;
#pragma unroll
    for (int rr = 0; rr < 4; ++rr) {
      const long grow = grow0 + rr;
      const long idx = grow * g.ldc + gcol;
      const float vv = v[rr] + bias + bf2f(g.residb[idx]) + g.srow[(grow >> 8) * 2048 + gcol];
      Ch[idx] = f2bf(vv);
    }
  }
}

// ============ 128x128 single-buffered kernel (m97 structure), T2-swizzled ============
// (256,4): occupancy ~41%, MfmaUtil ~43%. R14 A/B: XCD remap regresses — identity only.
template <int EPI>
__global__ __launch_bounds__(256, 4) void gemm_bt(GemmArgs g) {
  const int tid = threadIdx.x;
  const int lane = tid & 63;
  const int wave = tid >> 6;
  const int wm = wave >> 1, wn = wave & 1;
  const int bz = (int)blockIdx.z >> 3, hz = (int)blockIdx.z & 7;
  const long mBase = (long)blockIdx.x * 128;
  const long nBase = (long)blockIdx.y * 128;
  const unsigned short* Ab = g.A + bz * g.sAb + hz * g.sAh;
  const unsigned short* Bb = g.B + bz * g.sBb + hz * g.sBh;

  __shared__ __align__(16) unsigned short Asm[128 * 64];
  __shared__ __align__(16) unsigned short Bsm[128 * 64];

  f32x4 acc[4][4] = {};

  for (int kt = 0; kt < g.K; kt += 64) {
#pragma unroll
    for (int i = 0; i < 4; ++i) {
      const int u = i * 256 + tid;
      const int rr = u >> 3;
      const int cc = (((u & 7) ^ (rr & 7)) << 3);  // pre-swizzled source chunk
      gload16(Ab + (mBase + rr) * g.lda + kt + cc, Asm + (size_t)u * 8);
      gload16(Bb + (nBase + rr) * g.ldb + kt + cc, Bsm + (size_t)u * 8);
    }
    __syncthreads();
#pragma unroll
    for (int ks = 0; ks < 64; ks += 32) {
      const int kof = ks + ((lane >> 4) << 3);
      bf16x8v a[4], b[4];
#pragma unroll
      for (int mi = 0; mi < 4; ++mi) {
        const int row = wm * 64 + mi * 16 + (lane & 15);
        a[mi] = *(const bf16x8v*)&Asm[row * 64 + (kof ^ ((row & 7) << 3))];
      }
#pragma unroll
      for (int ni = 0; ni < 4; ++ni) {
        const int row = wn * 64 + ni * 16 + (lane & 15);
        b[ni] = *(const bf16x8v*)&Bsm[row * 64 + (kof ^ ((row & 7) << 3))];
      }
#pragma unroll
      for (int mi = 0; mi < 4; ++mi)
#pragma unroll
        for (int ni = 0; ni < 4; ++ni)
          acc[mi][ni] = __builtin_amdgcn_mfma_f32_16x16x32_bf16(a[mi], b[ni], acc[mi][ni], 0, 0, 0);
    }
    __syncthreads();
  }

  char* Cb = g.C + bz * g.sCb + hz * g.sCh;
#pragma unroll
  for (int mi = 0; mi < 4; ++mi) {
    const long grow0 = mBase + wm * 64 + mi * 16 + ((lane >> 4) << 2);
#pragma unroll
    for (int ni = 0; ni < 4; ++ni)
      epi_frag<EPI>(g, Cb, bz, hz, grow0, nBase + wn * 64 + ni * 16 + (lane & 15), acc[mi][ni]);
  }
}

// ============ 256x256 8-phase kernel, m201-faithful: READ-AHEAD ds_reads ============
// Phase = { ds_read subtile (top, BEFORE barrier) ; stage 1 half ; s_barrier ;
//           lgkmcnt(0)+sched_barrier(0) [rule #18] ; setprio(1) 16xMFMA setprio(0) ;
//           [P4 only: vmcnt(6)] ; s_barrier }.
// The read-ahead is the piece R6-R8 lacked: it offsets the 2 waves/SIMD so one
// issues LDS/DMA while the other runs MFMA (role-split; T5 pays).
// vmcnt FIFO (2 loads/half): one vmcnt(6)/tile retires exactly tile t+1's 4 halves.
template <int EPI>
__global__ __launch_bounds__(512, 2) void gemm8p(GemmArgs g) {
  const int tid = threadIdx.x;
  const int lane = tid & 63;
  const int wave = tid >> 6;
  const int wm = wave >> 2;       // 0..1
  const int wn = wave & 3;        // 0..3
  const long mBase = (long)blockIdx.x * 256;
  const long nBase = (long)blockIdx.y * 256;
  const unsigned short* Ab = g.A + mBase * g.lda;
  const unsigned short* Bb = g.B + nBase * g.ldb;

  __shared__ __align__(16) unsigned short Asm[2][2][128 * 64];  // [buf][half]
  __shared__ __align__(16) unsigned short Bsm[2][2][128 * 64];

  f32x4 acc[8][4] = {};
  bf16x8v a[4][2], b[2][2];
  const int nt = g.K >> 6;
  const int lrow = lane & 15;
  const int kof0 = (lane >> 4) << 3;
  const int lxor = (lane & 7) << 3;

#define STAGE_A(buf, mh, kt)                                                     \
  {                                                                              \
    _Pragma("unroll")                                                            \
    for (int j = 0; j < 2; ++j) {                                                \
      const int u = j * 512 + tid;                                               \
      const int rl = u >> 3;                                                     \
      const long r = rl + (rl & 64) + (mh) * 64;                                 \
      const int cc = (((u & 7) ^ (rl & 7)) << 3);                                \
      gload16(Ab + r * g.lda + (kt) + cc, &Asm[buf][mh][(size_t)u * 8]);         \
    }                                                                            \
  }
#define STAGE_B(buf, nh, kt)                                                     \
  {                                                                              \
    _Pragma("unroll")                                                            \
    for (int j = 0; j < 2; ++j) {                                                \
      const int u = j * 512 + tid;                                               \
      const int rl = u >> 3;                                                     \
      const long r = rl + (rl & 96) + (nh) * 32;                                 \
      const int cc = (((u & 7) ^ (rl & 7)) << 3);                                \
      gload16(Bb + r * g.ldb + (kt) + cc, &Bsm[buf][nh][(size_t)u * 8]);         \
    }                                                                            \
  }
#define LOAD_A(buf, mh)                                                          \
  {                                                                              \
    _Pragma("unroll")                                                            \
    for (int mi = 0; mi < 4; ++mi) {                                             \
      const int rl = wm * 64 + mi * 16 + lrow;                                   \
      _Pragma("unroll")                                                          \
      for (int ks = 0; ks < 2; ++ks)                                             \
        a[mi][ks] = *(const bf16x8v*)&Asm[buf][mh][rl * 64 + ((ks * 32 + kof0) ^ lxor)]; \
    }                                                                            \
  }
#define LOAD_B(buf, nh)                                                          \
  {                                                                              \
    _Pragma("unroll")                                                            \
    for (int ni = 0; ni < 2; ++ni) {                                             \
      const int rl = wn * 32 + ni * 16 + lrow;                                   \
      _Pragma("unroll")                                                          \
      for (int ks = 0; ks < 2; ++ks)                                             \
        b[ni][ks] = *(const bf16x8v*)&Bsm[buf][nh][rl * 64 + ((ks * 32 + kof0) ^ lxor)]; \
    }                                                                            \
  }
#define MFMA_Q(mh, nh)                                                           \
  {                                                                              \
    __builtin_amdgcn_s_setprio(1);                                               \
    _Pragma("unroll")                                                            \
    for (int mi = 0; mi < 4; ++mi)                                               \
      _Pragma("unroll")                                                          \
      for (int ni = 0; ni < 2; ++ni)                                             \
        _Pragma("unroll")                                                        \
        for (int ks = 0; ks < 2; ++ks)                                           \
          acc[(mh) * 4 + mi][(nh) * 2 + ni] = __builtin_amdgcn_mfma_f32_16x16x32_bf16( \
              a[mi][ks], b[ni][ks], acc[(mh) * 4 + mi][(nh) * 2 + ni], 0, 0, 0); \
    __builtin_amdgcn_s_setprio(0);                                               \
  }
#define BAR()  __builtin_amdgcn_s_barrier(); asm volatile("" ::: "memory");
#define LGKM() asm volatile("s_waitcnt lgkmcnt(0)" ::: "memory"); \
               __builtin_amdgcn_sched_barrier(0);

  // prologue: tile0 (4 halves) -> full publish; then t1 minus B0 (6 loads in flight)
  STAGE_A(0, 0, 0); STAGE_B(0, 1, 0); STAGE_A(0, 1, 0); STAGE_B(0, 0, 0);
  asm volatile("s_waitcnt vmcnt(0)" ::: "memory");
  BAR();
  STAGE_A(1, 0, 64); STAGE_B(1, 1, 64); STAGE_A(1, 1, 64);

  for (int t = 0; t < nt; ++t) {
    const int cb = t & 1, nb = cb ^ 1;
    const int kt2 = (t + 2) << 6;
    // P1 (mh0,nh0): reads ahead of barrier; stage B0(t+1)
    LOAD_A(cb, 0); LOAD_B(cb, 0);
    if (t + 1 < nt) STAGE_B(nb, 0, (t + 1) << 6);
    BAR(); LGKM();
    MFMA_Q(0, 0);
    BAR();
    // P2 (mh0,nh1): reads B1(t); stage A0(t+2) (A0(t) reads drained at P1)
    LOAD_B(cb, 1);
    if (t + 2 < nt) STAGE_A(cb, 0, kt2);
    BAR(); LGKM();
    MFMA_Q(0, 1);
    BAR();
    // P3 (mh1,nh1): reads A1(t); stage B1(t+2)
    LOAD_A(cb, 1);
    if (t + 2 < nt) STAGE_B(cb, 1, kt2);
    BAR(); LGKM();
    MFMA_Q(1, 1);
    BAR();
    // P4 (mh1,nh0): re-reads B0(t); stage A1(t+2); per-tile vmcnt before bar#2
    LOAD_B(cb, 0);
    if (t + 2 < nt) STAGE_A(cb, 1, kt2);
    BAR(); LGKM();
    MFMA_Q(1, 0);
    if (t < nt - 2)       { asm volatile("s_waitcnt vmcnt(6)" ::: "memory"); }
    else if (t == nt - 2) { asm volatile("s_waitcnt vmcnt(0)" ::: "memory"); }
    BAR();
  }
#undef STAGE_A
#undef STAGE_B
#undef LOAD_A
#undef LOAD_B
#undef MFMA_Q
#undef BAR
#undef LGKM

  char* Cb = g.C;
#pragma unroll
  for (int fi = 0; fi < 8; ++fi) {
    const long grow0 = mBase + wm * 128 + fi * 16 + ((lane >> 4) << 2);
#pragma unroll
    for (int fj = 0; fj < 4; ++fj)
      epi_frag<EPI>(g, Cb, 0, 0, grow0, nBase + wn * 64 + fj * 16 + (lane & 15), acc[fi][fj]);
  }
}

extern "C" void kernel_launch(void* const* d_in, const int* in_sizes, int n_in,
                              void* d_out, int out_size, void* d_ws, size_t ws_size,
                              hipStream_t stream) {
  (void)in_sizes; (void)n_in; (void)out_size;
  const float* x     = (const float*)d_in[0];
  const float* Wq    = (const float*)d_in[1];
  const float* bq    = (const float*)d_in[2];
  const float* Wk    = (const float*)d_in[3];
  const float* bk    = (const float*)d_in[4];
  const float* Wv    = (const float*)d_in[5];
  const float* bv    = (const float*)d_in[6];
  const float* Wo    = (const float*)d_in[7];
  const float* bo    = (const float*)d_in[8];
  const float* gamma = (const float*)d_in[9];
  const float* beta  = (const float*)d_in[10];
  float* out = (float*)d_out;

  const long M = 16384, D = 2048;
  char* ws = (char*)d_ws;
  size_t o = 0;
  unsigned short* xbf = (unsigned short*)(ws + o); o += (size_t)M * D * 2;
  unsigned short* wqT = (unsigned short*)(ws + o); o += (size_t)D * D * 2;  // contiguous:
  unsigned short* wkT = (unsigned short*)(ws + o); o += (size_t)D * D * 2;  //  [wqT|wkT|wvT]
  unsigned short* wvT = (unsigned short*)(ws + o); o += (size_t)D * D * 2;  //  = B[6144][2048]
  unsigned short* woT = (unsigned short*)(ws + o); o += (size_t)D * D * 2;
  unsigned short* qpro = (unsigned short*)(ws + o); o += (size_t)M * D * 2; // bf16 raw qproj / z
  unsigned short* qact = (unsigned short*)(ws + o); o += (size_t)M * D * 2;
  unsigned short* kact = (unsigned short*)(ws + o); o += (size_t)M * D * 2;
  unsigned short* vT   = (unsigned short*)(ws + o); o += (size_t)M * D * 2;
  unsigned short* P    = (unsigned short*)(ws + o); o += (size_t)512 * 65536 * 2;
  float* ksum = (float*)(ws + o); o += (size_t)64 * 2048 * 4;
  float* summ = (float*)(ws + o); o += (size_t)64 * 2048 * 4;
  float* srow = (float*)(ws + o); o += (size_t)64 * 2048 * 4;
  unsigned short* attn = xbf;  // alias: xbf dead after QKV GEMM (kept through PV output)
  float* spart = (float*)P;    // alias: P dead after PV-GEMM; 8*64*2048*4 = 4 MB
  if (ws_size < o) return;     // workspace too small -> clean fail

  cvt_f32_bf16<<<2048, 256, 0, stream>>>(x, xbf, M * D);
  Tr4Args t4;
  t4.src[0] = Wq; t4.src[1] = Wk; t4.src[2] = Wv; t4.src[3] = Wo;  // Wo rows 0-2047 = Wo1
  t4.dst[0] = wqT; t4.dst[1] = wkT; t4.dst[2] = wvT; t4.dst[3] = woT;
  tr_cvt4<<<dim3(32, 32, 4), 256, 0, stream>>>(t4);

  // fused QKV GEMM on the 8-phase kernel: B = [wqT|wkT|wvT] (6144 x 2048)
  GemmArgs a{};
  a.A = xbf; a.lda = 2048; a.sAb = 0; a.sAh = 0;
  a.B = wqT; a.ldb = 2048; a.sBb = 0; a.sBh = 0;
  a.C = (char*)qpro; a.ldc = 2048; a.sCb = 0; a.sCh = 0;
  a.K = 2048; a.aux = bq; a.sXb = 0; a.sXh = 0;
  a.residb = nullptr; a.srow = nullptr; a.out2 = qact;
  a.bk2 = bk; a.bv2 = bv; a.kact2 = kact; a.vt2 = vT;
  gemm8p<6><<<dim3(64, 24), 512, 0, stream>>>(a);

  colsum_bf16<<<dim3(8, 64), 256, 0, stream>>>(kact, ksum, 256, 1.0f);

  GemmArgs sA{};
  sA.A = qact; sA.lda = 2048; sA.sAb = 256 * 2048; sA.sAh = 256;
  sA.B = kact; sA.ldb = 2048; sA.sBb = 256 * 2048; sA.sBh = 256;
  sA.C = (char*)P; sA.ldc = 256; sA.sCb = 8L * 65536 * 2; sA.sCh = 65536L * 2;
  sA.K = 256; sA.aux = ksum; sA.sXb = 2048; sA.sXh = 256;
  sA.residb = nullptr; sA.srow = nullptr; sA.out2 = nullptr;
  gemm_bt<3><<<dim3(2, 2, 512), 256, 0, stream>>>(sA);

  GemmArgs tA{};
  tA.A = P; tA.lda = 256; tA.sAb = 8L * 65536; tA.sAh = 65536;
  tA.B = vT; tA.ldb = 256; tA.sBb = 2048L * 256; tA.sBh = 256 * 256;
  tA.C = (char*)attn; tA.ldc = 2048; tA.sCb = 256L * 2048 * 2; tA.sCh = 256 * 2;
  tA.K = 256; tA.aux = nullptr; tA.sXb = 0; tA.sXh = 0;
  tA.residb = nullptr; tA.srow = nullptr; tA.out2 = nullptr;
  gemm_bt<4><<<dim3(2, 2, 512), 256, 0, stream>>>(tA);

  colsum_bf16<<<dim3(8, 64), 256, 0, stream>>>(attn, summ, 256, 1.0f / 256.0f);
  srow_part<<<dim3(8, 64, 8), 256, 0, stream>>>(summ, Wo + (size_t)2048 * 2048, spart);
  srow_sum<<<dim3(8, 64), 256, 0, stream>>>(spart, srow);

  GemmArgs zA{};
  zA.A = attn; zA.lda = 2048; zA.sAb = 0; zA.sAh = 0;
  zA.B = woT; zA.ldb = 2048; zA.sBb = 0; zA.sBh = 0;
  zA.C = (char*)qpro; zA.ldc = 2048; zA.sCb = 0; zA.sCh = 0;  // in-place bf16 z over qproj
  zA.K = 2048; zA.aux = bo; zA.sXb = 0; zA.sXh = 0;
  zA.residb = qpro; zA.srow = srow; zA.out2 = nullptr;
  gemm_bt<5><<<dim3(128, 16, 1), 256, 0, stream>>>(zA);

  ln_k<<<16384, 256, 0, stream>>>(qpro, gamma, beta, out);
}

// Round 17
// 1030.487 us; speedup vs baseline: 1.0274x; 1.0274x over previous
//
#include <hip/hip_runtime.h>
#include <hip/hip_bf16.h>

typedef __attribute__((ext_vector_type(8))) __bf16 bf16x8v;
typedef __attribute__((ext_vector_type(4))) float f32x4;
typedef __attribute__((ext_vector_type(4))) unsigned short u16x4;
typedef __attribute__((ext_vector_type(8))) unsigned short u16x8;

#define LN_EPS 1e-6f

__device__ __forceinline__ unsigned short f2bf(float f) {
  union { float f; unsigned int u; } v; v.f = f;
  unsigned int r = v.u + 0x7fffu + ((v.u >> 16) & 1u);  // RNE
  return (unsigned short)(r >> 16);
}
__device__ __forceinline__ float bf2f(unsigned short u) {
  union { unsigned int u; float f; } v; v.u = ((unsigned int)u) << 16;
  return v.f;
}
__device__ __forceinline__ float elu1(float x) {
  return x > 0.f ? x + 1.f : __expf(x);  // elu(x)+1
}
__device__ __forceinline__ void gload16(const void* g, void* l) {
  __builtin_amdgcn_global_load_lds((__attribute__((address_space(1))) void*)g,
                                   (__attribute__((address_space(3))) void*)l,
                                   16, 0, 0);
}

// ---------------- f32 -> bf16 convert (vectorized) ----------------
__global__ __launch_bounds__(256) void cvt_f32_bf16(const float* __restrict__ in,
                                                    unsigned short* __restrict__ out, long n) {
  long stride = (long)gridDim.x * 256 * 8;
  for (long i = ((long)blockIdx.x * 256 + threadIdx.x) * 8; i < n; i += stride) {
    float4 a = *(const float4*)(in + i);
    float4 b = *(const float4*)(in + i + 4);
    u16x8 o;
    o[0] = f2bf(a.x); o[1] = f2bf(a.y); o[2] = f2bf(a.z); o[3] = f2bf(a.w);
    o[4] = f2bf(b.x); o[5] = f2bf(b.y); o[6] = f2bf(b.z); o[7] = f2bf(b.w);
    *(u16x8*)(out + i) = o;
  }
}

// ---------- transpose + convert, 4 matrices in one launch (z selects) ----------
struct Tr4Args { const float* src[4]; unsigned short* dst[4]; };
__global__ __launch_bounds__(256) void tr_cvt4(Tr4Args t4) {
  __shared__ float t[64][65];
  const float* in = t4.src[blockIdx.z];
  unsigned short* out = t4.dst[blockIdx.z];
  int r0 = blockIdx.y * 64, c0 = blockIdx.x * 64;
  for (int idx = threadIdx.x; idx < 4096; idx += 256) {
    int r = idx >> 6, c = idx & 63;
    t[r][c] = in[(long)(r0 + r) * 2048 + c0 + c];
  }
  __syncthreads();
  for (int idx = threadIdx.x; idx < 4096; idx += 256) {
    int c = idx >> 6, r = idx & 63;
    out[(long)(c0 + c) * 2048 + r0 + r] = f2bf(t[r][c]);
  }
}

// ---------------- column sum over `rows` rows per batch (bf16 in, f32 out) ----------------
__global__ __launch_bounds__(256) void colsum_bf16(const unsigned short* __restrict__ in,
                                                   float* __restrict__ out, int rows, float scale) {
  int b = blockIdx.y;
  int col = blockIdx.x * 256 + threadIdx.x;
  const unsigned short* p = in + (long)b * rows * 2048 + col;
  float acc = 0.f;
  for (int s = 0; s < rows; ++s) acc += bf2f(p[(long)s * 2048]);
  out[(long)b * 2048 + col] = acc * scale;
}

// ---------------- srow: two-stage k-split rank-64 matmul (R12-validated) ----------------
__global__ __launch_bounds__(256) void srow_part(const float* __restrict__ summ,
                                                 const float* __restrict__ Wo2,
                                                 float* __restrict__ part) {
  int col = blockIdx.x * 256 + threadIdx.x;
  int b = blockIdx.y;
  int k0 = blockIdx.z * 256;
  const float* s = summ + (long)b * 2048 + k0;
  const float* w = Wo2 + (long)k0 * 2048 + col;
  float acc = 0.f;
#pragma unroll 8
  for (int k = 0; k < 256; ++k) acc += s[k] * w[(long)k * 2048];
  part[((long)blockIdx.z * 64 + b) * 2048 + col] = acc;
}
__global__ __launch_bounds__(256) void srow_sum(const float* __restrict__ part,
                                                float* __restrict__ srow) {
  int col = blockIdx.x * 256 + threadIdx.x;
  int b = blockIdx.y;
  float acc = 0.f;
#pragma unroll
  for (int kb = 0; kb < 8; ++kb) acc += part[((long)kb * 64 + b) * 2048 + col];
  srow[(long)b * 2048 + col] = acc;
}

// ---------------- LayerNorm over rows of 2048 (bf16 z input) ----------------
__global__ __launch_bounds__(256) void ln_k(const unsigned short* __restrict__ z,
                                            const float* __restrict__ gamma,
                                            const float* __restrict__ beta,
                                            float* __restrict__ out) {
  long row = blockIdx.x;
  int t = threadIdx.x;
  u16x8 zv = *(const u16x8*)(z + row * 2048 + t * 8);
  float zf[8];
  float s = 0.f, q = 0.f;
#pragma unroll
  for (int j = 0; j < 8; ++j) {
    zf[j] = bf2f(zv[j]);
    s += zf[j];
    q += zf[j] * zf[j];
  }
#pragma unroll
  for (int o = 32; o >= 1; o >>= 1) { s += __shfl_xor(s, o); q += __shfl_xor(q, o); }
  __shared__ float ss[4], qq[4];
  if ((t & 63) == 0) { ss[t >> 6] = s; qq[t >> 6] = q; }
  __syncthreads();
  s = ss[0] + ss[1] + ss[2] + ss[3];
  q = qq[0] + qq[1] + qq[2] + qq[3];
  float mu = s * (1.f / 2048.f);
  float var = q * (1.f / 2048.f) - mu * mu;
  float rstd = rsqrtf(var + LN_EPS);
  float4 g1 = *(const float4*)(gamma + t * 8);
  float4 g2 = *(const float4*)(gamma + t * 8 + 4);
  float4 b1 = *(const float4*)(beta + t * 8);
  float4 b2 = *(const float4*)(beta + t * 8 + 4);
  float4 o1, o2;
  o1.x = (zf[0] - mu) * rstd * g1.x + b1.x;
  o1.y = (zf[1] - mu) * rstd * g1.y + b1.y;
  o1.z = (zf[2] - mu) * rstd * g1.z + b1.z;
  o1.w = (zf[3] - mu) * rstd * g1.w + b1.w;
  o2.x = (zf[4] - mu) * rstd * g2.x + b2.x;
  o2.y = (zf[5] - mu) * rstd * g2.y + b2.y;
  o2.z = (zf[6] - mu) * rstd * g2.z + b2.z;
  o2.w = (zf[7] - mu) * rstd * g2.w + b2.w;
  *(float4*)(out + row * 2048 + t * 8) = o1;
  *(float4*)(out + row * 2048 + t * 8 + 4) = o2;
}

struct GemmArgs {
  const unsigned short* A; long lda, sAb, sAh;   // element strides
  const unsigned short* B; long ldb, sBb, sBh;
  char* C; long ldc, sCb, sCh;                   // ldc elements, sC* bytes
  int K;
  const float* aux; long sXb, sXh;               // bias or divisor (element strides)
  const unsigned short* residb;                  // EPI 5 (bf16 residual)
  const float* srow;                             // EPI 5
  unsigned short* out2;                          // EPI 6 (qact)
  const float* bk2;                              // EPI 6
  const float* bv2;                              // EPI 6
  unsigned short* kact2;                         // EPI 6
  unsigned short* vt2;                           // EPI 6
};

// ---------------- shared epilogue (per 16x16 fragment) ----------------
// EPI 3: scores divide->bf16 | EPI 4: plain bf16 | EPI 5: z=v+bias+resid+srow -> bf16
// EPI 6: fused QKV — wsel=gcol>>11: 0=qproj(bf16 raw + elu), 1=k elu, 2=v transposed
template <int EPI>
__device__ __forceinline__ void epi_frag(const GemmArgs& g, char* Cb, int bz, int hz,
                                         long grow0, long gcol, f32x4 v) {
  if (EPI == 6) {
    const int wsel = (int)(gcol >> 11);
    const long cw = gcol & 2047;
    if (wsel == 0) {
      const float bias = g.aux[cw];
      unsigned short* Ch = (unsigned short*)Cb;
#pragma unroll
      for (int rr = 0; rr < 4; ++rr) {
        const long idx = (grow0 + rr) * 2048 + cw;
        const float vv = v[rr] + bias;
        Ch[idx] = f2bf(vv);
        g.out2[idx] = f2bf(elu1(vv));
      }
    } else if (wsel == 1) {
      const float bias = g.bk2[cw];
#pragma unroll
      for (int rr = 0; rr < 4; ++rr)
        g.kact2[(grow0 + rr) * 2048 + cw] = f2bf(elu1(v[rr] + bias));
    } else {
      const float bias = g.bv2[cw];
      const long batch = grow0 >> 8;
      const int sloc = (int)(grow0 & 255);
      u16x4 pk;
#pragma unroll
      for (int rr = 0; rr < 4; ++rr) pk[rr] = f2bf(v[rr] + bias);
      *(u16x4*)(g.vt2 + (batch * 2048 + cw) * 256 + sloc) = pk;
    }
  } else if (EPI == 3) {
    const float* divs = g.aux + bz * g.sXb + hz * g.sXh;
    const float d = divs[gcol] + LN_EPS;
    unsigned short* Ch = (unsigned short*)Cb;
#pragma unroll
    for (int rr = 0; rr < 4; ++rr)
      Ch[(grow0 + rr) * g.ldc + gcol] = f2bf(v[rr] / d);
  } else if (EPI == 4) {
    unsigned short* Ch = (unsigned short*)Cb;
#pragma unroll
    for (int rr = 0; rr < 4; ++rr)
      Ch[(grow0 + rr) * g.ldc + gcol] = f2bf(v[rr]);
  } else {  // EPI 5
    const float bias = g.aux[gcol];
    unsigned short* Ch = (unsigned short*)Cb;
#pragma unroll
    for (int rr = 0; rr < 4; ++rr) {
      const long grow = grow0 + rr;
      const long idx = grow * g.ldc + gcol;
      const float vv = v[rr] + bias + bf2f(g.residb[idx]) + g.srow[(grow >> 8) * 2048 + gcol];
      Ch[idx] = f2bf(vv);
    }
  }
}

// ============ 128x128 single-buffered kernel (m97 structure), T2-swizzled ============
// (256,4): occupancy ~43%, MfmaUtil ~43.6% on merged QKV = 943 TF effective
// (103% of the m97-structure reference ceiling, m103).
// R14 A/B: XCD-chunked remap REGRESSES (-20%, FETCH +40%) — identity mapping only.
// R6/R7/R8/R16: 8-phase deep-pipeline variants all lose to this high-TLP shallow
// structure here (1 block/CU at 128KB LDS starves both DMA and MFMA pipes).
template <int EPI>
__global__ __launch_bounds__(256, 4) void gemm_bt(GemmArgs g) {
  const int tid = threadIdx.x;
  const int lane = tid & 63;
  const int wave = tid >> 6;
  const int wm = wave >> 1, wn = wave & 1;
  const int bz = (int)blockIdx.z >> 3, hz = (int)blockIdx.z & 7;
  const long mBase = (long)blockIdx.x * 128;
  const long nBase = (long)blockIdx.y * 128;
  const unsigned short* Ab = g.A + bz * g.sAb + hz * g.sAh;
  const unsigned short* Bb = g.B + bz * g.sBb + hz * g.sBh;

  __shared__ __align__(16) unsigned short Asm[128 * 64];
  __shared__ __align__(16) unsigned short Bsm[128 * 64];

  f32x4 acc[4][4] = {};

  for (int kt = 0; kt < g.K; kt += 64) {
#pragma unroll
    for (int i = 0; i < 4; ++i) {
      const int u = i * 256 + tid;
      const int rr = u >> 3;
      const int cc = (((u & 7) ^ (rr & 7)) << 3);  // pre-swizzled source chunk
      gload16(Ab + (mBase + rr) * g.lda + kt + cc, Asm + (size_t)u * 8);
      gload16(Bb + (nBase + rr) * g.ldb + kt + cc, Bsm + (size_t)u * 8);
    }
    __syncthreads();
#pragma unroll
    for (int ks = 0; ks < 64; ks += 32) {
      const int kof = ks + ((lane >> 4) << 3);
      bf16x8v a[4], b[4];
#pragma unroll
      for (int mi = 0; mi < 4; ++mi) {
        const int row = wm * 64 + mi * 16 + (lane & 15);
        a[mi] = *(const bf16x8v*)&Asm[row * 64 + (kof ^ ((row & 7) << 3))];
      }
#pragma unroll
      for (int ni = 0; ni < 4; ++ni) {
        const int row = wn * 64 + ni * 16 + (lane & 15);
        b[ni] = *(const bf16x8v*)&Bsm[row * 64 + (kof ^ ((row & 7) << 3))];
      }
#pragma unroll
      for (int mi = 0; mi < 4; ++mi)
#pragma unroll
        for (int ni = 0; ni < 4; ++ni)
          acc[mi][ni] = __builtin_amdgcn_mfma_f32_16x16x32_bf16(a[mi], b[ni], acc[mi][ni], 0, 0, 0);
    }
    __syncthreads();
  }

  char* Cb = g.C + bz * g.sCb + hz * g.sCh;
#pragma unroll
  for (int mi = 0; mi < 4; ++mi) {
    const long grow0 = mBase + wm * 64 + mi * 16 + ((lane >> 4) << 2);
#pragma unroll
    for (int ni = 0; ni < 4; ++ni)
      epi_frag<EPI>(g, Cb, bz, hz, grow0, nBase + wn * 64 + ni * 16 + (lane & 15), acc[mi][ni]);
  }
}

extern "C" void kernel_launch(void* const* d_in, const int* in_sizes, int n_in,
                              void* d_out, int out_size, void* d_ws, size_t ws_size,
                              hipStream_t stream) {
  (void)in_sizes; (void)n_in; (void)out_size;
  const float* x     = (const float*)d_in[0];
  const float* Wq    = (const float*)d_in[1];
  const float* bq    = (const float*)d_in[2];
  const float* Wk    = (const float*)d_in[3];
  const float* bk    = (const float*)d_in[4];
  const float* Wv    = (const float*)d_in[5];
  const float* bv    = (const float*)d_in[6];
  const float* Wo    = (const float*)d_in[7];
  const float* bo    = (const float*)d_in[8];
  const float* gamma = (const float*)d_in[9];
  const float* beta  = (const float*)d_in[10];
  float* out = (float*)d_out;

  const long M = 16384, D = 2048;
  char* ws = (char*)d_ws;
  size_t o = 0;
  unsigned short* xbf = (unsigned short*)(ws + o); o += (size_t)M * D * 2;
  unsigned short* wqT = (unsigned short*)(ws + o); o += (size_t)D * D * 2;  // contiguous:
  unsigned short* wkT = (unsigned short*)(ws + o); o += (size_t)D * D * 2;  //  [wqT|wkT|wvT]
  unsigned short* wvT = (unsigned short*)(ws + o); o += (size_t)D * D * 2;  //  = B[6144][2048]
  unsigned short* woT = (unsigned short*)(ws + o); o += (size_t)D * D * 2;
  unsigned short* qpro = (unsigned short*)(ws + o); o += (size_t)M * D * 2; // bf16 raw qproj / z
  unsigned short* qact = (unsigned short*)(ws + o); o += (size_t)M * D * 2;
  unsigned short* kact = (unsigned short*)(ws + o); o += (size_t)M * D * 2;
  unsigned short* vT   = (unsigned short*)(ws + o); o += (size_t)M * D * 2;
  unsigned short* P    = (unsigned short*)(ws + o); o += (size_t)512 * 65536 * 2;
  float* ksum = (float*)(ws + o); o += (size_t)64 * 2048 * 4;
  float* summ = (float*)(ws + o); o += (size_t)64 * 2048 * 4;
  float* srow = (float*)(ws + o); o += (size_t)64 * 2048 * 4;
  unsigned short* attn = xbf;  // alias: xbf dead after QKV GEMM (kept through PV output)
  float* spart = (float*)P;    // alias: P dead after PV-GEMM; 8*64*2048*4 = 4 MB
  if (ws_size < o) return;     // workspace too small -> clean fail

  cvt_f32_bf16<<<2048, 256, 0, stream>>>(x, xbf, M * D);
  Tr4Args t4;
  t4.src[0] = Wq; t4.src[1] = Wk; t4.src[2] = Wv; t4.src[3] = Wo;  // Wo rows 0-2047 = Wo1
  t4.dst[0] = wqT; t4.dst[1] = wkT; t4.dst[2] = wvT; t4.dst[3] = woT;
  tr_cvt4<<<dim3(32, 32, 4), 256, 0, stream>>>(t4);

  // fused QKV GEMM: B = [wqT|wkT|wvT] (6144 x 2048), EPI6 branches per 2048-col range
  GemmArgs a{};
  a.A = xbf; a.lda = 2048; a.sAb = 0; a.sAh = 0;
  a.B = wqT; a.ldb = 2048; a.sBb = 0; a.sBh = 0;
  a.C = (char*)qpro; a.ldc = 2048; a.sCb = 0; a.sCh = 0;
  a.K = 2048; a.aux = bq; a.sXb = 0; a.sXh = 0;
  a.residb = nullptr; a.srow = nullptr; a.out2 = qact;
  a.bk2 = bk; a.bv2 = bv; a.kact2 = kact; a.vt2 = vT;
  gemm_bt<6><<<dim3(128, 48, 1), 256, 0, stream>>>(a);

  colsum_bf16<<<dim3(8, 64), 256, 0, stream>>>(kact, ksum, 256, 1.0f);

  GemmArgs sA{};
  sA.A = qact; sA.lda = 2048; sA.sAb = 256 * 2048; sA.sAh = 256;
  sA.B = kact; sA.ldb = 2048; sA.sBb = 256 * 2048; sA.sBh = 256;
  sA.C = (char*)P; sA.ldc = 256; sA.sCb = 8L * 65536 * 2; sA.sCh = 65536L * 2;
  sA.K = 256; sA.aux = ksum; sA.sXb = 2048; sA.sXh = 256;
  sA.residb = nullptr; sA.srow = nullptr; sA.out2 = nullptr;
  gemm_bt<3><<<dim3(2, 2, 512), 256, 0, stream>>>(sA);

  GemmArgs tA{};
  tA.A = P; tA.lda = 256; tA.sAb = 8L * 65536; tA.sAh = 65536;
  tA.B = vT; tA.ldb = 256; tA.sBb = 2048L * 256; tA.sBh = 256 * 256;
  tA.C = (char*)attn; tA.ldc = 2048; tA.sCb = 256L * 2048 * 2; tA.sCh = 256 * 2;
  tA.K = 256; tA.aux = nullptr; tA.sXb = 0; tA.sXh = 0;
  tA.residb = nullptr; tA.srow = nullptr; tA.out2 = nullptr;
  gemm_bt<4><<<dim3(2, 2, 512), 256, 0, stream>>>(tA);

  colsum_bf16<<<dim3(8, 64), 256, 0, stream>>>(attn, summ, 256, 1.0f / 256.0f);
  srow_part<<<dim3(8, 64, 8), 256, 0, stream>>>(summ, Wo + (size_t)2048 * 2048, spart);
  srow_sum<<<dim3(8, 64), 256, 0, stream>>>(spart, srow);

  GemmArgs zA{};
  zA.A = attn; zA.lda = 2048; zA.sAb = 0; zA.sAh = 0;
  zA.B = woT; zA.ldb = 2048; zA.sBb = 0; zA.sBh = 0;
  zA.C = (char*)qpro; zA.ldc = 2048; zA.sCb = 0; zA.sCh = 0;  // in-place bf16 z over qproj
  zA.K = 2048; zA.aux = bo; zA.sXb = 0; zA.sXh = 0;
  zA.residb = qpro; zA.srow = srow; zA.out2 = nullptr;
  gemm_bt<5><<<dim3(128, 16, 1), 256, 0, stream>>>(zA);

  ln_k<<<16384, 256, 0, stream>>>(qpro, gamma, beta, out);
}